// Round 1
// baseline (4412.449 us; speedup 1.0000x reference)
//
#include <hip/hip_runtime.h>
#include <math.h>

namespace {
constexpr int kBatch = 65536;
constexpr int kSteps = 60;
constexpr int kHid   = 128;
constexpr int kSlots = 4;

constexpr float kDT        = 1.0f / 12.0f;
constexpr float kLam       = 0.01f;
constexpr float kTexp      = 5.0f;
constexpr float kPrincipal = 100.0f;
constexpr float kGmdb      = 100.0f;
constexpr float kFee       = 0.0196f;
}

// One thread per path; blockIdx.y selects the step-slot (s = slot, slot+4, ...).
// All weight indices are wave-uniform -> scalar (s_load) weight fetches.
__global__ __launch_bounds__(256) void va_step_kernel(
    const float* __restrict__ spots,
    const float* __restrict__ W1,   // [2,128] row-major
    const float* __restrict__ b1,   // [128]
    const float* __restrict__ W2,   // [128,128] row-major
    const float* __restrict__ b2,   // [128]
    const float* __restrict__ W3,   // [128,1]
    const float* __restrict__ b3,   // [1]
    float* __restrict__ partial)    // [kSlots, kBatch]
{
    const int path = blockIdx.x * 256 + threadIdx.x;
    const int slot = blockIdx.y;
    const float b3v = b3[0];

    float pnl = 0.0f;

    for (int s = slot; s < kSteps; s += kSlots) {
        const float t         = (float)s * kDT;
        const float spot      = spots[s * kBatch + path];
        const float spot_next = spots[(s + 1) * kBatch + path];

        // Layer 1: h1[j] = relu(spot*W1[0,j] + t*W1[1,j] + b1[j])
        float h1[kHid];
        #pragma unroll
        for (int j = 0; j < kHid; ++j) {
            h1[j] = fmaxf(fmaf(spot, W1[j], fmaf(t, W1[kHid + j], b1[j])), 0.0f);
        }

        // Layers 2+3 fused, k-tiled by 8 (8 independent accumulators for ILP).
        float outv = b3v;
        #pragma unroll 1
        for (int kt = 0; kt < kHid; kt += 8) {
            float acc[8];
            #pragma unroll
            for (int u = 0; u < 8; ++u) acc[u] = b2[kt + u];

            #pragma unroll 4
            for (int j = 0; j < kHid; ++j) {
                const float hj = h1[j];
                #pragma unroll
                for (int u = 0; u < 8; ++u)
                    acc[u] = fmaf(hj, W2[j * kHid + kt + u], acc[u]);
            }

            #pragma unroll
            for (int u = 0; u < 8; ++u)
                outv = fmaf(fmaxf(acc[u], 0.0f), W3[kt + u], outv);
        }

        // Finance terms
        float delta = -(outv * outv);
        delta = delta * fminf(expf(-0.01f * delta), 1.0f);   // == delta (delta<=0), kept for fidelity
        delta = delta * ((1.0f - expf(-kLam * (kTexp - t))) * kPrincipal);

        const float account = kPrincipal * spot * expf(-kFee * t);  // S0 == 1
        const float elt     = expf(-kLam * t);
        const float fee     = kFee * kDT * account * elt;
        const float payout  = kLam * kDT * fmaxf(kGmdb - account, 0.0f) * elt;

        pnl += (fee - payout) + delta * (spot_next - spot);
    }

    partial[slot * kBatch + path] = pnl;
}

__global__ __launch_bounds__(256) void va_reduce_kernel(
    const float* __restrict__ partial, float* __restrict__ out)
{
    const int p = blockIdx.x * 256 + threadIdx.x;
    const float v01 = partial[p] + partial[kBatch + p];
    const float v23 = partial[2 * kBatch + p] + partial[3 * kBatch + p];
    out[p] = v01 + v23;
}

extern "C" void kernel_launch(void* const* d_in, const int* in_sizes, int n_in,
                              void* d_out, int out_size, void* d_ws, size_t ws_size,
                              hipStream_t stream)
{
    const float* spots = (const float*)d_in[0];
    const float* W1    = (const float*)d_in[1];
    const float* b1    = (const float*)d_in[2];
    const float* W2    = (const float*)d_in[3];
    const float* b2    = (const float*)d_in[4];
    const float* W3    = (const float*)d_in[5];
    const float* b3    = (const float*)d_in[6];
    float* out     = (float*)d_out;
    float* partial = (float*)d_ws;   // kSlots * kBatch floats = 1 MiB

    dim3 grid(kBatch / 256, kSlots);
    va_step_kernel<<<grid, dim3(256), 0, stream>>>(spots, W1, b1, W2, b2, W3, b3, partial);
    va_reduce_kernel<<<kBatch / 256, dim3(256), 0, stream>>>(partial, out);
}

// Round 2
// 63.954 us; speedup vs baseline: 68.9945x; 68.9945x over previous
//
#include <hip/hip_runtime.h>
#include <math.h>

namespace {
constexpr int kBatch = 65536;
constexpr int kSteps = 60;
constexpr int kHid   = 128;
constexpr int kNodes = 2048;                 // table nodes per step
constexpr float kInvDx = 128.0f;             // 1 / (16.0/2048)
constexpr float kDx    = 1.0f / 128.0f;

constexpr float kDT        = 1.0f / 12.0f;
constexpr float kLam       = 0.01f;
constexpr float kTexp      = 5.0f;
constexpr float kPrincipal = 100.0f;
constexpr float kGmdb      = 100.0f;
constexpr float kFee       = 0.0196f;
}

// Build tab[s][n] = (delta_scaled, fee - payout) at spot = n/128, t = s/12.
// One thread per (s, n). s is wave-uniform (2048 % 64 == 0), so all weight
// indices are wave-uniform -> scalar-cache s_loads; acc[128] statically
// indexed (inner o-loop fully unrolled) -> stays in VGPRs; h1 never stored.
__global__ __launch_bounds__(256) void va_build_table(
    const float* __restrict__ W1,   // [2,128]
    const float* __restrict__ b1,   // [128]
    const float* __restrict__ W2,   // [128,128]
    const float* __restrict__ b2,   // [128]
    const float* __restrict__ W3,   // [128]
    const float* __restrict__ b3,   // [1]
    float2* __restrict__ tab)       // [kSteps, kNodes]
{
    const int tid = blockIdx.x * 256 + threadIdx.x;   // 60*2048 threads
    const int s   = tid >> 11;
    const int n   = tid & (kNodes - 1);
    const float t    = (float)s * kDT;
    const float spot = (float)n * kDx;

    float acc[kHid];
    #pragma unroll
    for (int o = 0; o < kHid; ++o) acc[o] = b2[o];

    #pragma unroll 2
    for (int j = 0; j < kHid; ++j) {
        const float hj = fmaxf(fmaf(spot, W1[j], fmaf(t, W1[kHid + j], b1[j])), 0.0f);
        #pragma unroll
        for (int o = 0; o < kHid; ++o)
            acc[o] = fmaf(hj, W2[j * kHid + o], acc[o]);
    }

    float outv = b3[0];
    #pragma unroll
    for (int o = 0; o < kHid; ++o)
        outv = fmaf(fmaxf(acc[o], 0.0f), W3[o], outv);

    float delta = -(outv * outv);
    delta *= fminf(expf(-0.01f * delta), 1.0f);          // == 1 (delta<=0), fidelity
    delta *= (1.0f - expf(-kLam * (kTexp - t))) * kPrincipal;

    const float elt     = expf(-kLam * t);
    const float account = kPrincipal * spot * expf(-kFee * t);
    const float fee     = kFee * kDT * account * elt;
    const float payout  = kLam * kDT * fmaxf(kGmdb - account, 0.0f) * elt;

    tab[tid] = make_float2(delta, fee - payout);
}

// One thread per path: walk 60 steps, lerp (delta, feepay) from the table.
__global__ __launch_bounds__(256) void va_main_kernel(
    const float* __restrict__ spots,
    const float2* __restrict__ tab,
    float* __restrict__ out)
{
    const int path = blockIdx.x * 256 + threadIdx.x;

    float pnl  = 0.0f;
    float spot = spots[path];   // s = 0 row

    for (int s = 0; s < kSteps; ++s) {
        const float spot_next = spots[(s + 1) * kBatch + path];

        const float x  = spot * kInvDx;
        int i = (int)x;
        i = i < 0 ? 0 : (i > kNodes - 2 ? kNodes - 2 : i);
        float fr = x - (float)i;
        fr = fminf(fmaxf(fr, 0.0f), 1.0f);

        const float2 a = tab[s * kNodes + i];
        const float2 b = tab[s * kNodes + i + 1];
        const float delta  = fmaf(fr, b.x - a.x, a.x);
        const float feepay = fmaf(fr, b.y - a.y, a.y);

        pnl += feepay + delta * (spot_next - spot);
        spot = spot_next;
    }

    out[path] = pnl;
}

extern "C" void kernel_launch(void* const* d_in, const int* in_sizes, int n_in,
                              void* d_out, int out_size, void* d_ws, size_t ws_size,
                              hipStream_t stream)
{
    const float* spots = (const float*)d_in[0];
    const float* W1    = (const float*)d_in[1];
    const float* b1    = (const float*)d_in[2];
    const float* W2    = (const float*)d_in[3];
    const float* b2    = (const float*)d_in[4];
    const float* W3    = (const float*)d_in[5];
    const float* b3    = (const float*)d_in[6];
    float*  out = (float*)d_out;
    float2* tab = (float2*)d_ws;    // 60*2048*8 B = 983 KiB

    va_build_table<<<(kSteps * kNodes) / 256, dim3(256), 0, stream>>>(
        W1, b1, W2, b2, W3, b3, tab);
    va_main_kernel<<<kBatch / 256, dim3(256), 0, stream>>>(spots, tab, out);
}